// Round 12
// baseline (44.677 us; speedup 1.0000x reference)
//
#include <hip/hip_runtime.h>
#include <math.h>
#include <stdint.h>

#define EPS 1e-12f

typedef __attribute__((ext_vector_type(8))) short short8v;   // 8 bf16, 4 VGPRs
typedef __attribute__((ext_vector_type(8))) unsigned short us8;
typedef __attribute__((ext_vector_type(4))) float f32x4;

__device__ __forceinline__ unsigned short f2bf(float f) {
  union { float f; uint32_t u; } c; c.f = f;
  uint32_t u = c.u;
  uint32_t r = (u + 0x7FFFu + ((u >> 16) & 1u)) >> 16;  // RNE
  return (unsigned short)r;
}

__device__ __forceinline__ float bf2f(unsigned short v) {
  union { uint32_t u; float f; } c; c.u = ((uint32_t)v) << 16;
  return c.f;
}

__device__ __forceinline__ void gl_lds16(const void* g, void* l) {
  __builtin_amdgcn_global_load_lds(
      (const __attribute__((address_space(1))) unsigned int*)g,
      (__attribute__((address_space(3))) unsigned int*)l, 16, 0, 0);
}

// ---------------------------------------------------------------------------
// Workspace layout (bytes):
//   xT [16][64][64][64] bf16 @ 0       (8,388,608)  [n][h][w][c], c-chunks
//                                                   XOR-swizzled by w&7
//   Wb [9][128][64] bf16   @ 8388608   (147,456)    PLAIN layout (no swizzle)
// ---------------------------------------------------------------------------

// Prepass. Blocks 0..255: x-transpose, block = (n, 4-row h-band).
//   Reads:  contiguous 1KB runs per (plane, band chunk).
//   Writes: full 128B c-rows, 32KB contiguous per block.
// Blocks 256..287: weight normalize + transpose to plain [l][v][c].
__global__ __launch_bounds__(256) void prep_all(
    const float* __restrict__ x, const float* __restrict__ w,
    const float* __restrict__ q, unsigned short* __restrict__ xT,
    unsigned short* __restrict__ Wb) {
  __shared__ float raw[8][256];            // 8 planes x 256 pixels, 8 KB
  __shared__ unsigned short xt[256][64];   // persistent tile, 32 KB
  int b = blockIdx.x;
  int tid = threadIdx.x;

  if (b >= 256) {   // ---- weight path (32 blocks) ----
    int v = (b - 256) * 4 + (tid >> 6);
    int c = tid & 63;
    float qn = q[0] * 0.01f;
    float scale = qn * qn;
    const float* wp = w + (v * 64 + c) * 9;
    float vals[9];
    float ss = 0.f;
#pragma unroll
    for (int j = 0; j < 9; ++j) { vals[j] = wp[j]; ss += vals[j] * vals[j]; }
#pragma unroll
    for (int off = 32; off > 0; off >>= 1) ss += __shfl_xor(ss, off);
    float inv = 1.0f / (sqrtf(ss + EPS) + scale);
#pragma unroll
    for (int j = 0; j < 9; ++j)
      Wb[(j * 128 + v) * 64 + c] = f2bf(vals[j] * inv);   // plain layout
    return;
  }

  // ---- x path: b = n*16 + hb; band = rows hb*4..hb*4+3 (256 pixels) ----
  int n = b >> 4, hb = b & 15;
  int e = tid >> 5, i = tid & 31;
  const float* src0 = x + ((size_t)(n * 64 + e)) * 4096 + hb * 256 + i * 8;
#pragma unroll 1
  for (int cc = 0; cc < 8; ++cc) {
    if (cc) __syncthreads();             // raw reuse guard
    const float* src = src0 + (size_t)cc * 8 * 4096;
    float4 a0 = *(const float4*)src;
    float4 a1 = *(const float4*)(src + 4);
    *(float4*)&raw[e][i * 8] = a0;
    *(float4*)&raw[e][i * 8 + 4] = a1;
    __syncthreads();
    int pix = tid;                        // r = pix>>6, w = pix&63
    us8 pk;
#pragma unroll
    for (int e2 = 0; e2 < 8; ++e2) pk[e2] = f2bf(raw[e2][pix]);
    *(us8*)&xt[pix][((cc ^ (pix & 7)) * 8)] = pk;   // swizzle by w&7
  }
  __syncthreads();
  // streaming write: pixel per thread, full 128B row (rotated for LDS banks)
  int pix = tid;
  unsigned short* dst = xT + ((size_t)(n * 4096 + hb * 256 + pix)) * 64;
#pragma unroll
  for (int j = 0; j < 8; ++j) {
    int jj = (j + pix) & 7;
    *(us8*)(dst + jj * 8) = *(const us8*)&xt[pix][jj * 8];
  }
}

// Conv: 512 blocks x 256 thr (4 waves), 2 blocks/CU by grid.
// Tile = 2 h-rows x 64 w x 128 v. x staged via global_load_lds; channel
// sq-sum from staged bf16; weights read per-wave from global (L2-resident)
// -> ZERO barriers in the 9-l MFMA loop.
__global__ __launch_bounds__(256, 2) void conv_mfma(
    const unsigned short* __restrict__ xT, const unsigned short* __restrict__ Wb,
    const float* __restrict__ p, const float* __restrict__ q,
    float* __restrict__ out) {
  __shared__ unsigned short xs[4 * 66 * 64];  // [row][w+1][c] 33792 B
  __shared__ float sf[4 * 64];                // per-pixel channel sq-sums
  __shared__ float xiv[2 * 64];               // 1/(sqrt(box3x3)+scale)

  int b = blockIdx.x;              // 512 = 16 n x 32 row-pairs
  int n = b >> 5, hg = b & 31;
  int h0 = hg * 2;
  int tid = threadIdx.x;
  int lane = tid & 63, wid = tid >> 6;
  int wv = wid & 1, wp = wid >> 1;     // v-half, output row
  int lp = lane & 15, lg = lane >> 4;

  // ---- stage x rows h0-1..h0+2 via DMA: wave wid stages tile row wid ----
  {
    int hh = h0 - 1 + wid;
    unsigned short* dst = xs + wid * 4224 + 64;   // skip left pad column
    if ((unsigned)hh < 64u) {
      const unsigned short* src = xT + ((size_t)(n * 4096 + hh * 64)) * 64;
#pragma unroll
      for (int i = 0; i < 8; ++i)
        gl_lds16(src + i * 512 + lane * 8, dst + i * 512);
    } else {
      us8 z = {};
#pragma unroll
      for (int i = 0; i < 8; ++i)
        *(us8*)(dst + i * 512 + lane * 8) = z;
    }
  }
  // zero-pad columns w=-1 and w=64 for the 4 staged rows
  if (tid < 64) {
    int row = tid >> 4, side = (tid >> 3) & 1, j = tid & 7;
    us8 z = {};
    *(us8*)(xs + row * 4224 + (side ? 65 : 0) * 64 + j * 8) = z;
  }
  __syncthreads();   // xs ready (vmcnt drained)

  // ---- sf: channel sq-sum per staged pixel (from bf16) ----
  {
    int r = tid >> 6, ww = tid & 63;    // one pixel per thread
    const unsigned short* px = xs + r * 4224 + (ww + 1) * 64;
    float ss = 0.f;
#pragma unroll
    for (int j = 0; j < 8; ++j) {
      us8 v = *(const us8*)(px + ((j ^ (ww & 7)) * 8));
#pragma unroll
      for (int e = 0; e < 8; ++e) { float f = bf2f(v[e]); ss += f * f; }
    }
    sf[r * 64 + ww] = ss;
  }
  __syncthreads();   // sf ready

  if (tid < 128) {
    int r = tid >> 6, ww = tid & 63;
    float qn = q[0] * 0.01f;
    float scale = qn * qn;
    float a = 0.f;
#pragma unroll
    for (int dr = 0; dr < 3; ++dr) {
      const float* base = sf + (r + dr) * 64;
      a += base[ww];
      if (ww > 0) a += base[ww - 1];
      if (ww < 63) a += base[ww + 1];
    }
    xiv[r * 64 + ww] = 1.0f / (sqrtf(a + EPS) + scale);
  }
  __syncthreads();   // xiv ready; no more barriers below

  f32x4 acc[4][4];   // [pg][vg]
#pragma unroll
  for (int i = 0; i < 4; ++i)
#pragma unroll
    for (int j = 0; j < 4; ++j) acc[i][j] = (f32x4){0.f, 0.f, 0.f, 0.f};

  // per-lane global weight base: us8 index (wv*64+lp)*8 + lg
  const us8* wq = (const us8*)Wb + (wv * 64 + lp) * 8 + lg;

#pragma unroll
  for (int l = 0; l < 9; ++l) {
    const int a = l / 3, bs = l % 3;
    const unsigned short* xrow = xs + (wp + a) * 4224;
#pragma unroll
    for (int half = 0; half < 2; ++half) {
      const int cbase = half * 4;
      short8v av[4], bv[4];
#pragma unroll
      for (int vg = 0; vg < 4; ++vg)
        av[vg] = (short8v)wq[l * 1024 + vg * 128 + half * 4];  // L2-resident
#pragma unroll
      for (int pg = 0; pg < 4; ++pg) {
        int wx = pg * 16 + lp + bs - 1;          // -1..64; pad cols are zero
        bv[pg] = *(const short8v*)(xrow + (wx + 1) * 64 +
                                   ((cbase + lg) ^ (wx & 7)) * 8);
      }
#pragma unroll
      for (int pg = 0; pg < 4; ++pg)
#pragma unroll
        for (int vg = 0; vg < 4; ++vg)
          acc[pg][vg] = __builtin_amdgcn_mfma_f32_16x16x32_bf16(
              bv[pg], av[vg], acc[pg][vg], 0, 0, 0);
    }
  }

  // ---- epilogue: D[pixel][v]; lane: w4 = pg*16+lg*4, v = wv*64+vg*16+lp ----
  int h = h0 + wp;
#pragma unroll
  for (int vg = 0; vg < 4; ++vg) {
    int v = wv * 64 + vg * 16 + lp;
    float t0 = p[v] * 0.1f;
    float e = t0 * t0;
    float* ob = out + ((size_t)(n * 128 + v)) * 4096 + h * 64;
#pragma unroll
    for (int pg = 0; pg < 4; ++pg) {
      int w4 = pg * 16 + lg * 4;
      float4 xv = *(const float4*)&xiv[wp * 64 + w4];
      float yv[4] = {acc[pg][vg][0] * xv.x, acc[pg][vg][1] * xv.y,
                     acc[pg][vg][2] * xv.z, acc[pg][vg][3] * xv.w};
      f32x4 o;
#pragma unroll
      for (int r = 0; r < 4; ++r) {
        float y = yv[r];
        float t = fabsf(y) + EPS;
        float rv = exp2f(e * log2f(t));
        o[r] = (y == 0.0f) ? 0.0f : copysignf(rv, y);
      }
      *(f32x4*)(ob + w4) = o;
    }
  }
}

extern "C" void kernel_launch(void* const* d_in, const int* in_sizes, int n_in,
                              void* d_out, int out_size, void* d_ws, size_t ws_size,
                              hipStream_t stream) {
  const float* x = (const float*)d_in[0];   // [16,64,64,64]
  const float* w = (const float*)d_in[1];   // [128,64,9]
  const float* p = (const float*)d_in[2];   // [128]
  const float* q = (const float*)d_in[3];   // [1]
  float* out = (float*)d_out;               // [16,128,64,64]

  char* wsb = (char*)d_ws;
  unsigned short* xT = (unsigned short*)(wsb);
  unsigned short* Wb = (unsigned short*)(wsb + 8388608);

  prep_all<<<288, 256, 0, stream>>>(x, w, q, xT, Wb);
  conv_mfma<<<512, 256, 0, stream>>>(xT, Wb, p, q, out);
}